// Round 5
// baseline (294.852 us; speedup 1.0000x reference)
//
#include <hip/hip_runtime.h>
#include <math.h>

#define TOTAL_ANCHORS 87296
#define NTOPK 87040        // anchors in levels 0-3 (level 4 passes through)
#define NSEL 4256
#define NWORDS 67          // ceil(4256/64)
#define NPAD   4288        // 67*64, padded row count for word-major mask
#define MAXROUNDS 4300     // safety cap; progress guarantee => <= NSEL rounds
#define CANDMAX 8192       // per-level candidate buffer (keys with top16 >= T)

// ---------- helpers ----------
__device__ __forceinline__ float sigmoidf_(float x) {
    return 1.0f / (1.0f + expf(-x));
}
// monotone float->uint mapping (ascending)
__device__ __forceinline__ unsigned int f2s(float f) {
    unsigned int u = __float_as_uint(f);
    return u ^ ((u >> 31) ? 0xFFFFFFFFu : 0x80000000u);
}

struct InPtrs {
    const float* cls[5];
    const float* reg[5];
    const float* ctn[5];
    const float* scales;
};

// ---------- 1. decode: per-anchor score/label/box + sort key + top16 histogram --
__global__ __launch_bounds__(256) void decode_kernel(InPtrs in,
        unsigned long long* __restrict__ keys, float* __restrict__ scores,
        int* __restrict__ labels, float4* __restrict__ boxes,
        unsigned int* __restrict__ hist) {
    int g = blockIdx.x * 256 + threadIdx.x;
    if (g >= TOTAL_ANCHORS) return;
    int lv, base, W, stride;
    if (g < 65536)      { lv = 0; base = 0;     W = 256; stride = 8;   }
    else if (g < 81920) { lv = 1; base = 65536; W = 128; stride = 16;  }
    else if (g < 86016) { lv = 2; base = 81920; W = 64;  stride = 32;  }
    else if (g < 87040) { lv = 3; base = 86016; W = 32;  stride = 64;  }
    else                { lv = 4; base = 87040; W = 16;  stride = 128; }
    int p = g - base;
    int HW = W * W;
    int x = p & (W - 1);
    int y = p / W;
    const float* cls = in.cls[lv];
    float sctn = sigmoidf_(in.ctn[lv][p]);
    float best = -1.0f; int lbl = 0;
    for (int c = 0; c < 80; ++c) {
        float v = cls[c * HW + p];
        float pr = sqrtf(__fmul_rn(sigmoidf_(v), sctn));
        if (pr > best) { best = pr; lbl = c; }   // strict > : first-index argmax
    }
    float scale = in.scales[lv];
    float fs = (float)stride;
    const float* rg = in.reg[lv];
    float r0 = __fmul_rn(fmaxf(__fmul_rn(rg[0 * HW + p], scale), 0.0f), fs);
    float r1 = __fmul_rn(fmaxf(__fmul_rn(rg[1 * HW + p], scale), 0.0f), fs);
    float r2 = __fmul_rn(fmaxf(__fmul_rn(rg[2 * HW + p], scale), 0.0f), fs);
    float r3 = __fmul_rn(fmaxf(__fmul_rn(rg[3 * HW + p], scale), 0.0f), fs);
    float ax = __fmul_rn(__fadd_rn((float)x, 0.5f), fs);
    float ay = __fmul_rn(__fadd_rn((float)y, 0.5f), fs);
    float4 b;
    b.x = __fsub_rn(ax, r0);
    b.y = __fsub_rn(ay, r1);
    b.z = __fadd_rn(ax, r2);
    b.w = __fadd_rn(ay, r3);
    scores[g] = best;
    labels[g] = lbl;
    boxes[g]  = b;
    // key: score desc, local index asc on ties (lax.top_k semantics)
    unsigned long long key = ((unsigned long long)f2s(best) << 32) | (unsigned int)(~(unsigned int)p);
    keys[g] = key;
    if (g < NTOPK) atomicAdd(&hist[(lv << 16) + (unsigned int)(key >> 48)], 1u);
}

// ---------- 2a. select: exact top16 threshold per level from the histogram -----
// T = smallest 16-bit value with |{k : top16(k) >= T}| >= 1000.
__global__ __launch_bounds__(1024) void select_kernel(
        const unsigned int* __restrict__ hist, unsigned int* __restrict__ thr) {
    const int lvl = blockIdx.x;
    const unsigned int* base = hist + (lvl << 16);
    const int tid = threadIdx.x;
    __shared__ unsigned int csum[1024];
    unsigned int s = 0;
    #pragma unroll 8
    for (int b = tid * 64; b < tid * 64 + 64; ++b) s += base[b];
    csum[tid] = s;
    __syncthreads();
    // suffix inclusive scan: csum[c] = sum_{c' >= c} chunk_sum(c')
    for (int off = 1; off < 1024; off <<= 1) {
        unsigned int v = csum[tid] + ((tid + off < 1024) ? csum[tid + off] : 0u);
        __syncthreads();
        csum[tid] = v;
        __syncthreads();
    }
    unsigned int incl = csum[tid];
    unsigned int incl1 = (tid == 1023) ? 0u : csum[tid + 1];
    if (incl >= 1000u && incl1 < 1000u) {      // unique boundary chunk
        unsigned int running = incl1;
        for (int b = tid * 64 + 63; b >= tid * 64; --b) {
            running += base[b];
            if (running >= 1000u) { thr[lvl] = (unsigned int)b; break; }
        }
    }
}

// ---------- 2b. gather: all keys with top16 >= T[level] -> candidate buffer ----
__global__ __launch_bounds__(256) void gather_kernel(
        const unsigned long long* __restrict__ keys,
        const unsigned int* __restrict__ thr,
        unsigned long long* __restrict__ cand, unsigned int* __restrict__ cnt) {
    int g = blockIdx.x * 256 + threadIdx.x;
    if (g >= NTOPK) return;
    int lvl;
    if (g < 65536)      lvl = 0;
    else if (g < 81920) lvl = 1;
    else if (g < 86016) lvl = 2;
    else                lvl = 3;
    unsigned long long k = keys[g];
    if ((unsigned int)(k >> 48) >= thr[lvl]) {
        unsigned int pos = atomicAdd(&cnt[lvl], 1u);
        if (pos < CANDMAX) cand[(lvl << 13) + pos] = k;   // order nondet; sort fixes
    }
}

// ---------- 2c. finalsort: bitonic-sort candidates desc, take top-1000 ---------
__global__ __launch_bounds__(1024) void finalsort_kernel(
        const unsigned long long* __restrict__ cand,
        const unsigned int* __restrict__ cnt,
        unsigned long long* __restrict__ sel) {
    const int lvl = blockIdx.x;
    const int tid = threadIdx.x;
    __shared__ unsigned long long sk[CANDMAX];
    int n = (int)cnt[lvl];
    if (n > CANDMAX) n = CANDMAX;
    int P = 1024;
    while (P < n) P <<= 1;                     // <= 8192
    for (int i = tid; i < P; i += 1024)
        sk[i] = (i < n) ? cand[(lvl << 13) + i] : 0ull;   // 0 sinks (real keys > 0)
    __syncthreads();
    for (int kk = 2; kk <= P; kk <<= 1) {
        for (int j = kk >> 1; j > 0; j >>= 1) {
            for (int i = tid; i < P; i += 1024) {
                int ixj = i ^ j;
                if (ixj > i) {
                    unsigned long long a = sk[i], b = sk[ixj];
                    bool sw = ((i & kk) == 0) ? (a < b) : (a > b);
                    if (sw) { sk[i] = b; sk[ixj] = a; }
                }
            }
            __syncthreads();
        }
    }
    if (tid < 1000) sel[lvl * 1000 + tid] = sk[tid];
}

// ---------- 3. fused mid: finalize + sort-l4 + merge-rank (one block, 1024 thr) ----
__device__ __forceinline__ int count_greater(const unsigned long long* A, int n,
                                             unsigned long long x) {
    int lo = 0, hi = n;
    while (lo < hi) { int m = (lo + hi) >> 1; if (A[m] > x) lo = m + 1; else hi = m; }
    return lo;
}
__global__ __launch_bounds__(1024) void mid_kernel(
        const unsigned long long* __restrict__ sel,
        const float* __restrict__ scores, const int* __restrict__ labels,
        const float4* __restrict__ boxes, float* __restrict__ out,
        int* __restrict__ order, float4* __restrict__ sbox,
        float* __restrict__ sarea, int* __restrict__ svalid) {
    __shared__ unsigned long long ekey[NSEL];
    __shared__ unsigned long long sk4[256];
    const int tid = threadIdx.x;
    float4 bxs[5]; float ars[5]; int vls[5];
    // ---- phase 1: finalize (gather top-k, write outputs, build NMS entries) ----
    #pragma unroll
    for (int k = 0; k < 5; ++k) {
        int pos = tid + k * 1024;
        if (pos < NSEL) {
            int g;
            if (pos < 4000) {
                int lv = pos / 1000;
                const int offs_[4] = {0, 65536, 81920, 86016};
                unsigned long long key = sel[pos];
                unsigned int p = ~((unsigned int)(key & 0xFFFFFFFFull));
                g = offs_[lv] + (int)p;
            } else {
                g = 87040 + (pos - 4000);   // level 4: raw order
            }
            float sc = scores[g];
            int lb = labels[g];
            float4 bx = boxes[g];
            const float inv = 1.0f / 2048.0f;   // /2048 == *2^-11 exactly
            out[pos * 4 + 0] = fminf(fmaxf(__fmul_rn(bx.x, inv), 0.0f), 1.0f);
            out[pos * 4 + 1] = fminf(fmaxf(__fmul_rn(bx.y, inv), 0.0f), 1.0f);
            out[pos * 4 + 2] = fminf(fmaxf(__fmul_rn(bx.z, inv), 0.0f), 1.0f);
            out[pos * 4 + 3] = fminf(fmaxf(__fmul_rn(bx.w, inv), 0.0f), 1.0f);
            out[17024 + pos] = sc;
            out[21280 + pos] = (float)lb;
            out[25536 + pos] = 0.0f;            // keep default; sweep sets kept=1
            float off = __fmul_rn((float)lb, 100000.0f);
            float4 eb;
            eb.x = __fadd_rn(bx.x, off); eb.y = __fadd_rn(bx.y, off);
            eb.z = __fadd_rn(bx.z, off); eb.w = __fadd_rn(bx.w, off);
            bxs[k] = eb;
            ars[k] = __fmul_rn(__fsub_rn(eb.z, eb.x), __fsub_rn(eb.w, eb.y));
            int valid = (sc >= 0.05f) ? 1 : 0;
            vls[k] = valid;
            float effs = valid ? sc : -INFINITY;
            ekey[pos] = ((unsigned long long)f2s(effs) << 32) | (unsigned int)(~(unsigned int)pos);
        }
    }
    __syncthreads();
    // ---- phase 2: bitonic-sort the 256 level-4 keys (only unsorted chunk) ----
    if (tid < 256) sk4[tid] = ekey[4000 + tid];
    __syncthreads();
    for (int kk = 2; kk <= 256; kk <<= 1) {
        for (int j = kk >> 1; j > 0; j >>= 1) {
            if (tid < 256) {
                int ixj = tid ^ j;
                if (ixj > tid) {
                    unsigned long long a = sk4[tid], b = sk4[ixj];
                    bool sw = ((tid & kk) == 0) ? (a < b) : (a > b);
                    if (sw) { sk4[tid] = b; sk4[ixj] = a; }
                }
            }
            __syncthreads();
        }
    }
    // ---- phase 3: merge-rank (stable global sort via binary-search ranks) ----
    #pragma unroll
    for (int k = 0; k < 5; ++k) {
        int pos = tid + k * 1024;
        if (pos < NSEL) {
            unsigned long long x = ekey[pos];
            int rank = count_greater(ekey,        1000, x)
                     + count_greater(ekey + 1000, 1000, x)
                     + count_greater(ekey + 2000, 1000, x)
                     + count_greater(ekey + 3000, 1000, x)
                     + count_greater(sk4,          256, x);
            order[rank]  = pos;
            sbox[rank]   = bxs[k];
            sarea[rank]  = ars[k];
            svalid[rank] = vls[k];
        }
    }
}

// ---------- 4. IoU bitmask, WORD-MAJOR layout: maskC[w*NPAD + row] ----------
__global__ __launch_bounds__(64) void mask_kernel(
        const float4* __restrict__ sbox, const float* __restrict__ sarea,
        unsigned long long* __restrict__ maskC) {
    int colTile = blockIdx.x, rowTile = blockIdx.y;
    if (colTile > rowTile) return;
    __shared__ float4 cb[64];
    __shared__ float ca[64];
    int tid = threadIdx.x;
    int col0 = colTile * 64;
    int c = col0 + tid;
    if (c < NSEL) { cb[tid] = sbox[c]; ca[tid] = sarea[c]; }
    else { cb[tid] = make_float4(0.f, 0.f, 0.f, 0.f); ca[tid] = 0.f; }
    __syncthreads();
    int i = rowTile * 64 + tid;
    unsigned long long bits = 0ull;
    if (i < NSEL) {
        float4 b = sbox[i];
        float ar = sarea[i];
        for (int j = 0; j < 64; ++j) {
            float xx1 = fmaxf(b.x, cb[j].x);
            float yy1 = fmaxf(b.y, cb[j].y);
            float xx2 = fminf(b.z, cb[j].z);
            float yy2 = fminf(b.w, cb[j].w);
            float w = fmaxf(1e-10f, __fsub_rn(xx2, xx1));
            float h = fmaxf(1e-10f, __fsub_rn(yy2, yy1));
            float inter = __fmul_rn(w, h);
            float denom = __fadd_rn(__fsub_rn(__fadd_rn(ar, ca[j]), inter), 1e-14f);
            float ovr = __fdiv_rn(inter, denom);
            if (ovr > 0.6f) bits |= (1ull << j);
        }
    }
    maskC[(size_t)colTile * NPAD + i] = bits;   // coalesced; pad rows store 0
}

// ---------- 5. greedy sweep as PARALLEL FIXED-POINT ----------
__global__ __launch_bounds__(1024) void sweep_kernel(
        const unsigned long long* __restrict__ maskC,
        const int* __restrict__ order, const int* __restrict__ svalid,
        float* __restrict__ out_keep) {
    const int tid = threadIdx.x;
    const int lane = tid & 63;
    const int wave = tid >> 6;
    __shared__ unsigned long long keptL[NWORDS], unkL[NWORDS];
    __shared__ unsigned long long nk[NWORDS], nd[NWORDS];
    __shared__ int wflag[16];

    #pragma unroll
    for (int k = 0; k < 5; ++k) {
        int b = wave + 16 * k;
        if (b >= NWORDS) continue;
        int c = b * 64 + lane;
        int v = (c < NSEL) ? svalid[c] : 0;
        unsigned long long w = __ballot(v != 0);
        if (lane == 0) { unkL[b] = w; keptL[b] = 0ull; }
    }
    __syncthreads();

    for (int round = 0; round < MAXROUNDS; ++round) {
        #pragma unroll
        for (int k = 0; k < 5; ++k) {
            int b = wave + 16 * k;
            if (b >= NWORDS) continue;
            int c = b * 64 + lane;
            unsigned long long uw = unkL[b];
            bool dec = false, kp = false;
            if (uw) {
                bool myunk = (uw >> lane) & 1ull;
                if (myunk) {
                    unsigned long long accK = 0ull, accU = 0ull;
                    #pragma unroll 4
                    for (int w = 0; w < b; ++w) {
                        unsigned long long kw = keptL[w], uw2 = unkL[w];
                        if (kw | uw2) {
                            unsigned long long m = maskC[(size_t)w * NPAD + c];
                            accK |= m & kw;
                            accU |= m & uw2;
                        }
                    }
                    unsigned long long below = (1ull << lane) - 1ull;
                    unsigned long long md = maskC[(size_t)b * NPAD + c];
                    accK |= md & keptL[b] & below;
                    accU |= md & uw & below;
                    if (accK) { dec = true; }
                    else if (accU == 0ull) { dec = true; kp = true; }
                }
            }
            unsigned long long kb = __ballot(kp);
            unsigned long long db = __ballot(dec);
            if (lane == 0) { nk[b] = kb; nd[b] = db; }
        }
        __syncthreads();
        int any = 0;
        #pragma unroll
        for (int k = 0; k < 5; ++k) {
            int b = wave + 16 * k;
            if (b >= NWORDS) continue;
            unsigned long long db = nd[b];
            if (lane == 0) {
                keptL[b] |= nk[b];
                unkL[b]  &= ~db;
            }
            any |= (db != 0ull) ? 1 : 0;
        }
        if (lane == 0) wflag[wave] = any;
        __syncthreads();
        int anych = 0;
        #pragma unroll
        for (int w = 0; w < 16; ++w) anych |= wflag[w];
        if (!anych) break;
    }

    #pragma unroll
    for (int k = 0; k < 5; ++k) {
        int b = wave + 16 * k;
        if (b >= NWORDS) continue;
        int c = b * 64 + lane;
        if (c < NSEL && ((keptL[b] >> lane) & 1ull)) out_keep[order[c]] = 1.0f;
    }
}

// ---------- workspace layout (all 16B-aligned) ----------
constexpr size_t OFF_KEYS    = 0;                            // u64 * 87296
constexpr size_t OFF_SCORES  = OFF_KEYS    + 698368;         // f32 * 87296
constexpr size_t OFF_LABELS  = OFF_SCORES  + 349184;         // i32 * 87296
constexpr size_t OFF_BOXES   = OFF_LABELS  + 349184;         // f32x4 * 87296
constexpr size_t OFF_SEL     = OFF_BOXES   + 1396736;        // u64 * 4000
constexpr size_t OFF_ORDER   = OFF_SEL     + 32000;          // i32 * 4256
constexpr size_t OFF_SBOX    = OFF_ORDER   + 17024;          // f32x4 * 4256
constexpr size_t OFF_SAREA   = OFF_SBOX    + 68096;          // f32 * 4256
constexpr size_t OFF_SVALID  = OFF_SAREA   + 17024;          // i32 * 4256
constexpr size_t OFF_MASK    = OFF_SVALID  + 17024;          // u64 * NWORDS * NPAD
constexpr size_t OFF_HIST    = OFF_MASK    + (size_t)NWORDS * NPAD * 8;  // u32 * 4*65536
constexpr size_t OFF_CNT     = OFF_HIST    + 4u * 65536u * 4u;           // u32 * 4 (+pad)
constexpr size_t OFF_CAND    = OFF_CNT     + 64;             // u64 * 4 * CANDMAX
constexpr size_t HIST_ZERO_BYTES = 4u * 65536u * 4u + 64;    // hist + cnt in one memset

extern "C" void kernel_launch(void* const* d_in, const int* in_sizes, int n_in,
                              void* d_out, int out_size, void* d_ws, size_t ws_size,
                              hipStream_t stream) {
    (void)in_sizes; (void)n_in; (void)out_size; (void)ws_size;
    InPtrs P;
    for (int lv = 0; lv < 5; ++lv) {
        P.cls[lv] = (const float*)d_in[3 * lv + 0];
        P.reg[lv] = (const float*)d_in[3 * lv + 1];
        P.ctn[lv] = (const float*)d_in[3 * lv + 2];
    }
    P.scales = (const float*)d_in[15];

    char* ws = (char*)d_ws;
    unsigned long long* keys   = (unsigned long long*)(ws + OFF_KEYS);
    float*              scores = (float*)             (ws + OFF_SCORES);
    int*                labels = (int*)               (ws + OFF_LABELS);
    float4*             boxes  = (float4*)            (ws + OFF_BOXES);
    unsigned long long* sel    = (unsigned long long*)(ws + OFF_SEL);
    int*                order  = (int*)               (ws + OFF_ORDER);
    float4*             sbox   = (float4*)            (ws + OFF_SBOX);
    float*              sarea  = (float*)             (ws + OFF_SAREA);
    int*                svalid = (int*)               (ws + OFF_SVALID);
    unsigned long long* maskb  = (unsigned long long*)(ws + OFF_MASK);
    unsigned int*       hist   = (unsigned int*)      (ws + OFF_HIST);
    unsigned int*       cnt    = (unsigned int*)      (ws + OFF_CNT);
    unsigned long long* cand   = (unsigned long long*)(ws + OFF_CAND);
    float* out = (float*)d_out;

    hipMemsetAsync(hist, 0, HIST_ZERO_BYTES, stream);
    decode_kernel<<<TOTAL_ANCHORS / 256, 256, 0, stream>>>(P, keys, scores, labels, boxes, hist);
    select_kernel<<<4, 1024, 0, stream>>>(hist, cnt + 8);   // thr stored at cnt+8 (same memset region? no: separate) 
    // NOTE: thr must NOT be zero-initialized-dependent; select writes all 4 entries.
    gather_kernel<<<(NTOPK + 255) / 256, 256, 0, stream>>>(keys, cnt + 8, cand, cnt);
    finalsort_kernel<<<4, 1024, 0, stream>>>(cand, cnt, sel);
    mid_kernel<<<1, 1024, 0, stream>>>(sel, scores, labels, boxes, out,
                                       order, sbox, sarea, svalid);
    mask_kernel<<<dim3(NWORDS, NWORDS), 64, 0, stream>>>(sbox, sarea, maskb);
    sweep_kernel<<<1, 1024, 0, stream>>>(maskb, order, svalid, out + 25536);
}